// Round 10
// baseline (97.793 us; speedup 1.0000x reference)
//
#include <hip/hip_runtime.h>
#include <cstdint>

typedef __attribute__((ext_vector_type(8))) short bf16x8;
typedef __attribute__((ext_vector_type(4))) float f32x4;

#if __has_builtin(__builtin_amdgcn_exp2f)
#define EXP2F(x) __builtin_amdgcn_exp2f(x)
#else
#define EXP2F(x) exp2f(x)
#endif
#if __has_builtin(__builtin_amdgcn_rcpf)
#define RCPF(x) __builtin_amdgcn_rcpf(x)
#else
#define RCPF(x) (1.0f/(x))
#endif

#define C2LOG2E 2.885390081777927f   // 2*log2(e)
#define LOG2E   1.4426950408889634f

__device__ __forceinline__ unsigned int f2bf(float f) {
    union { float f; unsigned int u; } v; v.f = f;
    return ((v.u + 0x7FFFu + ((v.u >> 16) & 1u)) >> 16);
}
__device__ __forceinline__ float bf2f(unsigned short h) {
    union { unsigned int u; float f; } v; v.u = ((unsigned int)h) << 16; return v.f;
}

// ---- prep: X fp32->bf16 ; transpose W_ap, W_pa, W_po ----
__global__ void prep_kernel(const float* __restrict__ x, const float* __restrict__ W_ap,
                            const float* __restrict__ W_pa, const float* __restrict__ W_po,
                            unsigned short* __restrict__ Xb, float* __restrict__ Wt,
                            float* __restrict__ Wpat, float* __restrict__ Wpot) {
    int t = blockIdx.x * 256 + threadIdx.x;   // 32768 threads, 8 elems each
    const float* src = x + (size_t)t * 8;
    float4 a = *(const float4*)(src);
    float4 b = *(const float4*)(src + 4);
    unsigned int p0 = f2bf(a.x) | (f2bf(a.y) << 16);
    unsigned int p1 = f2bf(a.z) | (f2bf(a.w) << 16);
    unsigned int p2 = f2bf(b.x) | (f2bf(b.y) << 16);
    unsigned int p3 = f2bf(b.z) | (f2bf(b.w) << 16);
    *(int4*)(Xb + (size_t)t * 8) = make_int4((int)p0, (int)p1, (int)p2, (int)p3);
    if (t < 64 * 64) {
        int src_i = (t & 63) * 64 + (t >> 6);   // [d][o] -> [o][d]
        Wt[t]   = W_ap[src_i];
        Wpat[t] = W_pa[src_i];
        Wpot[t] = W_po[src_i];
    }
}

// ---- main: one block per (b,i); 2 waves split over the o-dim (32 o's each).
// Per-wave body ~70 unified regs -> fits the (128,6) 85-reg cap -> 6 waves/SIMD.
// (Bracketing: full-o body = ~100-128 regs caps at 4 waves/SIMD [R4]; 32-reg
//  o-split=4 body chokes the load pipeline [R6]; o-split=2 is the midpoint.)
__global__ __launch_bounds__(128, 6) void gat_kernel(
    const float* __restrict__ x, const float* __restrict__ b_ap, const float* __restrict__ att_w,
    const float* __restrict__ b_pa, const float* __restrict__ b_po,
    const float* __restrict__ gma, const float* __restrict__ bta,
    const float* __restrict__ rmean, const float* __restrict__ rvar,
    const unsigned short* __restrict__ Xb, const float* __restrict__ Wt,
    const float* __restrict__ Wpat, const float* __restrict__ Wpot,
    float* __restrict__ out)
{
    __shared__ float sScP[2][512];   // per-o-half score partials
    __shared__ float sP[512];        // normalized p
    __shared__ float sAgP[2][64];    // per-wave agg partials

    const int t  = threadIdx.x;
    const int l  = t & 63;
    const int w  = t >> 6;                     // o-half AND agg j-half owner
    // XCD swizzle: XCD k <-> batch... 4096 blocks = 8 x 512; one batch per XCD
    const int bid = blockIdx.x;
    const int ig  = (bid & 7) * 512 + (bid >> 3);
    const int b   = ig >> 9;
    const int lm = l & 15;
    const int lq = l >> 4;
    const unsigned short* __restrict__ Xg = Xb + (size_t)b * (512 * 64);
    const float* __restrict__ xi = x + (size_t)ig * 64;

    // ---- A-fragments for this wave's 32 o's, PRE-SCALED by 2*log2(e):
    // acc = C2LOG2E * S directly out of the MFMA.
    bf16x8 af[4];
    #pragma unroll
    for (int ks = 0; ks < 2; ++ks) {
        float4 xc0 = *(const float4*)(xi + ks * 32 + lq * 8);
        float4 xc1 = *(const float4*)(xi + ks * 32 + lq * 8 + 4);
        xc0.x *= C2LOG2E; xc0.y *= C2LOG2E; xc0.z *= C2LOG2E; xc0.w *= C2LOG2E;
        xc1.x *= C2LOG2E; xc1.y *= C2LOG2E; xc1.z *= C2LOG2E; xc1.w *= C2LOG2E;
        #pragma unroll
        for (int of = 0; of < 2; ++of) {
            const float* wr = Wt + (w * 32 + of * 16 + lm) * 64 + ks * 32 + lq * 8;
            float4 w0 = *(const float4*)(wr);
            float4 w1 = *(const float4*)(wr + 4);
            unsigned int p0 = f2bf(w0.x * xc0.x) | (f2bf(w0.y * xc0.y) << 16);
            unsigned int p1 = f2bf(w0.z * xc0.z) | (f2bf(w0.w * xc0.w) << 16);
            unsigned int p2 = f2bf(w1.x * xc1.x) | (f2bf(w1.y * xc1.y) << 16);
            unsigned int p3 = f2bf(w1.z * xc1.z) | (f2bf(w1.w * xc1.w) << 16);
            int4 pk = make_int4((int)p0, (int)p1, (int)p2, (int)p3);
            af[of * 2 + ks] = *reinterpret_cast<bf16x8*>(&pk);
        }
    }

    // ---- per-lane o-consts for 8 o's (o = w*32 + of*16 + lq*4 + r);
    // bias folded into the MFMA C-init (binit = C2LOG2E * b_ap, C/D layout).
    float n2a[8];
    f32x4 binit[2];
    float asum = 0.f;
    #pragma unroll
    for (int of = 0; of < 2; ++of) {
        #pragma unroll
        for (int r = 0; r < 4; ++r) {
            int o = w * 32 + of * 16 + lq * 4 + r;
            float a = att_w[o];
            n2a[of * 4 + r] = -2.f * a;
            binit[of][r]    = C2LOG2E * b_ap[o];
            asum += a;
        }
    }

    // ---- QK + tanh-score: all 32 j-tiles, this wave's 32 o's ----
    const unsigned short* xrow = Xg + lm * 64 + lq * 8;
    bf16x8 nb0 = *(const bf16x8*)(xrow);
    bf16x8 nb1 = *(const bf16x8*)(xrow + 32);
    for (int jt = 0; jt < 32; ++jt) {
        bf16x8 b0 = nb0, b1 = nb1;
        if (jt < 31) {
            nb0 = *(const bf16x8*)(xrow + (jt + 1) * 1024);
            nb1 = *(const bf16x8*)(xrow + (jt + 1) * 1024 + 32);
        }
        f32x4 acc0 = binit[0], acc1 = binit[1];
        acc0 = __builtin_amdgcn_mfma_f32_16x16x32_bf16(af[0], b0, acc0, 0, 0, 0);
        acc1 = __builtin_amdgcn_mfma_f32_16x16x32_bf16(af[2], b0, acc1, 0, 0, 0);
        acc0 = __builtin_amdgcn_mfma_f32_16x16x32_bf16(af[1], b1, acc0, 0, 0, 0);
        acc1 = __builtin_amdgcn_mfma_f32_16x16x32_bf16(af[3], b1, acc1, 0, 0, 0);
        // acc = C2LOG2E*(S+b): per elem = exp2, add, rcp, fma (2V + 2T)
        float pA = 0.f, pB = 0.f;
        #pragma unroll
        for (int r = 0; r < 4; ++r) {
            float e0 = EXP2F(acc0[r]);
            pA = fmaf(n2a[r], RCPF(1.f + e0), pA);
            float e1 = EXP2F(acc1[r]);
            pB = fmaf(n2a[4 + r], RCPF(1.f + e1), pB);
        }
        float part = asum + (pA + pB);
        part += __shfl_xor(part, 16);
        part += __shfl_xor(part, 32);
        if (l < 16) sScP[w][jt * 16 + l] = part;
    }
    __syncthreads();                 // barrier 1: both o-half partials in LDS

    // ---- softmax over 512 (redundant per wave; lane l holds j = l*8..l*8+7) ----
    float s0[8];
    {
        float4 a0 = *(const float4*)(&sScP[0][l * 8]);
        float4 a1 = *(const float4*)(&sScP[0][l * 8 + 4]);
        float4 c0 = *(const float4*)(&sScP[1][l * 8]);
        float4 c1 = *(const float4*)(&sScP[1][l * 8 + 4]);
        s0[0]=a0.x+c0.x; s0[1]=a0.y+c0.y; s0[2]=a0.z+c0.z; s0[3]=a0.w+c0.w;
        s0[4]=a1.x+c1.x; s0[5]=a1.y+c1.y; s0[6]=a1.z+c1.z; s0[7]=a1.w+c1.w;
    }
    float m = s0[0];
    #pragma unroll
    for (int e = 1; e < 8; ++e) m = fmaxf(m, s0[e]);
    #pragma unroll
    for (int o2 = 32; o2; o2 >>= 1) m = fmaxf(m, __shfl_xor(m, o2));
    float sm = 0.f;
    #pragma unroll
    for (int e = 0; e < 8; ++e) { s0[e] = EXP2F((s0[e] - m) * LOG2E); sm += s0[e]; }
    #pragma unroll
    for (int o2 = 32; o2; o2 >>= 1) sm += __shfl_xor(sm, o2);
    float inv = RCPF(sm);
    // write p for THIS wave's j-half: lanes [32w, 32w+32) own j = [256w, 256w+256)
    if ((l >> 5) == w) {
        float4 r0 = {s0[0]*inv, s0[1]*inv, s0[2]*inv, s0[3]*inv};
        float4 r1 = {s0[4]*inv, s0[5]*inv, s0[6]*inv, s0[7]*inv};
        *(float4*)(&sP[l * 8]) = r0;
        *(float4*)(&sP[l * 8 + 4]) = r1;
    }
    asm volatile("s_waitcnt lgkmcnt(0)" ::: "memory");   // wave-private RAW on own half

    // ---- agg partial over this wave's 256 j's ----
    {
        const int rs = l >> 3, c8 = (l & 7) * 8;
        float a8[8];
        #pragma unroll
        for (int e = 0; e < 8; ++e) a8[e] = 0.f;
        #pragma unroll 4
        for (int jb = 0; jb < 32; ++jb) {
            int j = w * 256 + jb * 8 + rs;
            float pj = sP[j];
            bf16x8 v = *(const bf16x8*)(Xg + j * 64 + c8);
            #pragma unroll
            for (int e = 0; e < 8; ++e)
                a8[e] = fmaf(bf2f((unsigned short)v[e]), pj, a8[e]);
        }
        #pragma unroll
        for (int e = 0; e < 8; ++e) {
            float v = a8[e];
            v += __shfl_xor(v, 8);
            v += __shfl_xor(v, 16);
            v += __shfl_xor(v, 32);
            a8[e] = v;
        }
        if (l < 8) {
            #pragma unroll
            for (int e = 0; e < 8; ++e) sAgP[w][l * 8 + e] = a8[e];
        }
    }
    __syncthreads();                 // barrier 2: both agg halves in LDS

    // ---- epilogue on wave 0: h[o=l] = agg@W_pa + x_i@W_po + biases ; BN ; SELU ----
    if (w == 0) {
        float hv = b_pa[l] + b_po[l];
        const float* wa = Wpat + l * 64;
        const float* wo = Wpot + l * 64;
        #pragma unroll 4
        for (int dc = 0; dc < 16; ++dc) {
            float4 g0 = *(const float4*)(&sAgP[0][dc * 4]);
            float4 g1 = *(const float4*)(&sAgP[1][dc * 4]);
            float4 ag = {g0.x + g1.x, g0.y + g1.y, g0.z + g1.z, g0.w + g1.w};
            float4 va = *(const float4*)(wa + dc * 4);
            float4 vo = *(const float4*)(wo + dc * 4);
            float4 xv = *(const float4*)(xi + dc * 4);
            hv = fmaf(ag.x, va.x, hv); hv = fmaf(ag.y, va.y, hv);
            hv = fmaf(ag.z, va.z, hv); hv = fmaf(ag.w, va.w, hv);
            hv = fmaf(xv.x, vo.x, hv); hv = fmaf(xv.y, vo.y, hv);
            hv = fmaf(xv.z, vo.z, hv); hv = fmaf(xv.w, vo.w, hv);
        }
        float istd = rsqrtf(rvar[l] + 1e-5f);
        hv = (hv - rmean[l]) * istd * gma[l] + bta[l];
        const float alpha = 1.6732632423543772f, scale = 1.0507009873554805f;
        float neg = alpha * (EXP2F(hv * LOG2E) - 1.0f);
        out[(size_t)ig * 64 + l] = scale * (hv > 0.f ? hv : neg);
    }
}

extern "C" void kernel_launch(void* const* d_in, const int* in_sizes, int n_in,
                              void* d_out, int out_size, void* d_ws, size_t ws_size,
                              hipStream_t stream) {
    const float* x     = (const float*)d_in[0];
    const float* W_ap  = (const float*)d_in[1];
    const float* b_ap  = (const float*)d_in[2];
    const float* att_w = (const float*)d_in[3];
    const float* W_pa  = (const float*)d_in[4];
    const float* b_pa  = (const float*)d_in[5];
    const float* W_po  = (const float*)d_in[6];
    const float* b_po  = (const float*)d_in[7];
    const float* gma   = (const float*)d_in[8];
    const float* bta   = (const float*)d_in[9];
    const float* rmean = (const float*)d_in[10];
    const float* rvar  = (const float*)d_in[11];

    char* ws = (char*)d_ws;
    unsigned short* Xb = (unsigned short*)ws;          // 512 KB bf16 X
    float* Wt          = (float*)(ws + 512 * 1024);    // 16 KB W_ap^T
    float* Wpat        = (float*)(ws + 528 * 1024);    // 16 KB W_pa^T
    float* Wpot        = (float*)(ws + 544 * 1024);    // 16 KB W_po^T
    float* out         = (float*)d_out;

    prep_kernel<<<128, 256, 0, stream>>>(x, W_ap, W_pa, W_po, Xb, Wt, Wpat, Wpot);
    gat_kernel<<<4096, 128, 0, stream>>>(x, b_ap, att_w, b_pa, b_po, gma, bta, rmean, rvar,
                                         Xb, Wt, Wpat, Wpot, out);
}